// Round 1
// baseline (440.343 us; speedup 1.0000x reference)
//
#include <hip/hip_runtime.h>

#define B_ 4
#define N_ 10000
#define D_ 64
#define C_ 2
#define E_ 160000
#define EPS_ 1e-10f

// y[bc*N + n] = {y1, y0} where y1 = x[b,n,:]·wa[c,0:64], y0 = x[b,n,:]·wa[c,64:128]
__global__ void gat_y(const float* __restrict__ x, const float* __restrict__ wa,
                      float2* __restrict__ y) {
    int bc = blockIdx.x / 40;              // 40 blocks of 256 cover N=10000
    int n  = (blockIdx.x % 40) * 256 + threadIdx.x;
    if (n >= N_) return;
    int b = bc / C_, c = bc % C_;
    const float4* xr = (const float4*)(x + ((size_t)b * N_ + n) * D_);
    const float4* w1 = (const float4*)(wa + (size_t)c * 2 * D_);   // uniform per block
    const float4* w0 = w1 + D_ / 4;
    float y1 = 0.f, y0 = 0.f;
#pragma unroll
    for (int i = 0; i < D_ / 4; ++i) {
        float4 xv = xr[i];
        float4 a  = w1[i];
        float4 bb = w0[i];
        y1 += xv.x * a.x  + xv.y * a.y  + xv.z * a.z  + xv.w * a.w;
        y0 += xv.x * bb.x + xv.y * bb.y + xv.z * bb.z + xv.w * bb.w;
    }
    y[(size_t)bc * N_ + n] = make_float2(y1, y0);
}

// per edge: score -> exp(leaky_relu) -> ee[], atomic denom[i0]
__global__ void gat_edge1(const int* __restrict__ eidx, const float2* __restrict__ y,
                          float* __restrict__ ee, float* __restrict__ denom) {
    int bc = blockIdx.x / 625;             // 625*256 == E
    int e  = (blockIdx.x % 625) * 256 + threadIdx.x;
    const int2* ep = (const int2*)eidx + (size_t)bc * E_;
    int2 ii = ep[e];                       // ii.x = idx[e,0], ii.y = idx[e,1]
    float2 ya = y[(size_t)bc * N_ + ii.y]; // a1 node
    float2 yb = y[(size_t)bc * N_ + ii.x]; // a2 node
    float s  = ya.x + yb.y;
    float lr = s > 0.f ? s : 0.2f * s;
    float ev = __expf(lr);
    ee[(size_t)bc * E_ + e] = ev;
    atomicAdd(&denom[(size_t)bc * N_ + ii.x], ev);
}

// one wave per edge, lane = d: r[i0,d] += alpha * x[i1,d]
__global__ void gat_edge2(const int* __restrict__ eidx, const float* __restrict__ x,
                          const float* __restrict__ ee, const float* __restrict__ denom,
                          float* __restrict__ r) {
    int lane = threadIdx.x & 63;
    int wid  = threadIdx.x >> 6;           // 4 waves/block
    int bc   = blockIdx.x / 40000;         // 40000*4 == E
    int e    = (blockIdx.x % 40000) * 4 + wid;
    size_t base = (size_t)bc * E_ + e;
    int i0 = eidx[base * 2];
    int i1 = eidx[base * 2 + 1];
    float ev  = ee[base];
    float den = denom[(size_t)bc * N_ + i1];   // NOTE: gathered by i1 (ref quirk)
    float alpha = ev / (den + EPS_);
    int b = bc / C_;
    float xv = x[((size_t)b * N_ + i1) * D_ + lane];
    atomicAdd(&r[((size_t)bc * N_ + i0) * D_ + lane], alpha * xv);
}

// out[b,n,d] = sigmoid(r[b,0,n,d]) + sigmoid(r[b,1,n,d])
__global__ void gat_out(const float* __restrict__ r, float* __restrict__ out) {
    int o4  = blockIdx.x * 256 + threadIdx.x;   // float4 index, total 640000
    int b   = o4 / (N_ * D_ / 4);
    int rem = o4 % (N_ * D_ / 4);
    const float4* r0 = (const float4*)r + (size_t)b * (C_ * N_ * D_ / 4) + rem;
    const float4* r1 = r0 + (N_ * D_ / 4);
    float4 v0 = *r0, v1 = *r1;
    float4 o;
    o.x = 1.f / (1.f + __expf(-v0.x)) + 1.f / (1.f + __expf(-v1.x));
    o.y = 1.f / (1.f + __expf(-v0.y)) + 1.f / (1.f + __expf(-v1.y));
    o.z = 1.f / (1.f + __expf(-v0.z)) + 1.f / (1.f + __expf(-v1.z));
    o.w = 1.f / (1.f + __expf(-v0.w)) + 1.f / (1.f + __expf(-v1.w));
    ((float4*)out)[o4] = o;
}

extern "C" void kernel_launch(void* const* d_in, const int* in_sizes, int n_in,
                              void* d_out, int out_size, void* d_ws, size_t ws_size,
                              hipStream_t stream) {
    const float* x    = (const float*)d_in[0];   // (B,N,D) f32
    const int*   eidx = (const int*)d_in[1];     // (B,C,E,2) i32
    const float* wa   = (const float*)d_in[2];   // (C,2D,1) f32
    float* out = (float*)d_out;

    float*  r     = (float*)d_ws;                        // B*C*N*D
    float*  denom = r + (size_t)B_ * C_ * N_ * D_;       // B*C*N
    float2* y     = (float2*)(denom + (size_t)B_ * C_ * N_); // B*C*N float2
    float*  ee    = (float*)(y + (size_t)B_ * C_ * N_);  // B*C*E

    // zero r + denom (contiguous); ws is poisoned 0xAA before every launch
    hipMemsetAsync(d_ws, 0,
                   ((size_t)B_ * C_ * N_ * D_ + (size_t)B_ * C_ * N_) * sizeof(float),
                   stream);

    gat_y    <<<B_ * C_ * 40,    256, 0, stream>>>(x, wa, y);
    gat_edge1<<<B_ * C_ * 625,   256, 0, stream>>>(eidx, y, ee, denom);
    gat_edge2<<<B_ * C_ * 40000, 256, 0, stream>>>(eidx, x, ee, denom, r);
    gat_out  <<<B_ * N_ * D_ / 4 / 256, 256, 0, stream>>>(r, out);
}

// Round 2
// 359.254 us; speedup vs baseline: 1.2257x; 1.2257x over previous
//
#include <hip/hip_runtime.h>

#define B_ 4
#define N_ 10000
#define D_ 64
#define C_ 2
#define E_ 160000
#define BC_ (B_ * C_)
#define EPS_ 1e-10f

// y[bc*N + n] = {y1, y0}: y1 = x[b,n,:]·wa[c,0:64], y0 = x[b,n,:]·wa[c,64:128]
__global__ void gat_y(const float* __restrict__ x, const float* __restrict__ wa,
                      float2* __restrict__ y) {
    int bc = blockIdx.x / 40;
    int n  = (blockIdx.x % 40) * 256 + threadIdx.x;
    if (n >= N_) return;
    int b = bc / C_, c = bc % C_;
    const float4* xr = (const float4*)(x + ((size_t)b * N_ + n) * D_);
    const float4* w1 = (const float4*)(wa + (size_t)c * 2 * D_);
    const float4* w0 = w1 + D_ / 4;
    float y1 = 0.f, y0 = 0.f;
#pragma unroll
    for (int i = 0; i < D_ / 4; ++i) {
        float4 xv = xr[i];
        float4 a  = w1[i];
        float4 bb = w0[i];
        y1 += xv.x * a.x  + xv.y * a.y  + xv.z * a.z  + xv.w * a.w;
        y0 += xv.x * bb.x + xv.y * bb.y + xv.z * bb.z + xv.w * bb.w;
    }
    y[(size_t)bc * N_ + n] = make_float2(y1, y0);
}

// histogram of destination i0 per (b,c)
__global__ void gat_hist(const int* __restrict__ eidx, int* __restrict__ cnt) {
    int bc = blockIdx.x / 625;
    int e  = (blockIdx.x % 625) * 256 + threadIdx.x;
    const int2* ep = (const int2*)eidx + (size_t)bc * E_;
    int i0 = ep[e].x;
    atomicAdd(&cnt[bc * N_ + i0], 1);
}

// exclusive scan per bc (one block each): cnt[bc][0..N) -> rs[bc][0..N], head copy
__global__ void gat_scan(const int* __restrict__ cnt, int* __restrict__ rs,
                         int* __restrict__ head) {
    int bc = blockIdx.x;
    __shared__ int sdata[256];
    __shared__ int s_carry;
    if (threadIdx.x == 0) s_carry = 0;
    __syncthreads();
    for (int chunk = 0; chunk < 40; ++chunk) {
        int i   = chunk * 256 + threadIdx.x;
        int val = (i < N_) ? cnt[bc * N_ + i] : 0;
        sdata[threadIdx.x] = val;
        __syncthreads();
        // Hillis-Steele inclusive scan over 256
#pragma unroll
        for (int off = 1; off < 256; off <<= 1) {
            int t = (threadIdx.x >= off) ? sdata[threadIdx.x - off] : 0;
            __syncthreads();
            sdata[threadIdx.x] += t;
            __syncthreads();
        }
        int carry = s_carry;
        int excl  = carry + sdata[threadIdx.x] - val;
        if (i < N_) {
            rs[bc * (N_ + 1) + i] = excl;
            head[bc * N_ + i]     = excl;
        }
        __syncthreads();
        if (threadIdx.x == 255) s_carry = carry + sdata[255];
        __syncthreads();
    }
    if (threadIdx.x == 0) rs[bc * (N_ + 1) + N_] = E_;
}

// per edge: ee from y; place (i1, ee) into CSR slot of destination i0
__global__ void gat_scatter(const int* __restrict__ eidx, const float2* __restrict__ y,
                            int* __restrict__ head, int* __restrict__ csr_i1,
                            float* __restrict__ csr_ee) {
    int bc = blockIdx.x / 625;
    int e  = (blockIdx.x % 625) * 256 + threadIdx.x;
    const int2* ep = (const int2*)eidx + (size_t)bc * E_;
    int2 ii = ep[e];                        // x = i0 (dst), y = i1 (src)
    float2 ya = y[(size_t)bc * N_ + ii.y];
    float2 yb = y[(size_t)bc * N_ + ii.x];
    float s  = ya.x + yb.y;
    float lr = s > 0.f ? s : 0.2f * s;
    float ev = __expf(lr);
    int pos = atomicAdd(&head[bc * N_ + ii.x], 1);
    csr_i1[(size_t)bc * E_ + pos] = ii.y;
    csr_ee[(size_t)bc * E_ + pos] = ev;
}

// denom[bc,n] = sum of csr_ee over n's segment (no atomics)
__global__ void gat_denom(const int* __restrict__ rs, const float* __restrict__ csr_ee,
                          float* __restrict__ denom) {
    int gid = blockIdx.x * 256 + threadIdx.x;   // 80000 threads
    if (gid >= BC_ * N_) return;
    int bc = gid / N_, n = gid % N_;
    int s = rs[bc * (N_ + 1) + n];
    int t = rs[bc * (N_ + 1) + n + 1];
    const float* ep = csr_ee + (size_t)bc * E_;
    float sum = 0.f;
    for (int j = s; j < t; ++j) sum += ep[j];
    denom[bc * N_ + n] = sum;
}

// wave per (b,n), lane = d: out = sum_c sigmoid( sum_seg alpha * x[i1,d] )
__global__ void gat_acc(const float* __restrict__ x, const int* __restrict__ rs,
                        const int* __restrict__ csr_i1, const float* __restrict__ csr_ee,
                        const float* __restrict__ denom, float* __restrict__ out) {
    int lane = threadIdx.x & 63;
    int wid  = blockIdx.x * 4 + (threadIdx.x >> 6);   // 0..B*N-1
    int b = wid / N_, n = wid % N_;
    const float* xb = x + (size_t)b * N_ * D_;
    float o = 0.f;
#pragma unroll
    for (int c = 0; c < C_; ++c) {
        int bc = b * C_ + c;
        int s = rs[bc * (N_ + 1) + n];
        int t = rs[bc * (N_ + 1) + n + 1];
        const int*   ip = csr_i1 + (size_t)bc * E_;
        const float* ep = csr_ee + (size_t)bc * E_;
        const float* dn = denom + bc * N_;
        float acc = 0.f;
        for (int j = s; j < t; ++j) {
            int   i1 = ip[j];
            float ev = ep[j];
            float al = ev / (dn[i1] + EPS_);
            acc += al * xb[i1 * D_ + lane];
        }
        o += 1.f / (1.f + __expf(-acc));
    }
    out[((size_t)b * N_ + n) * D_ + lane] = o;
}

extern "C" void kernel_launch(void* const* d_in, const int* in_sizes, int n_in,
                              void* d_out, int out_size, void* d_ws, size_t ws_size,
                              hipStream_t stream) {
    const float* x    = (const float*)d_in[0];   // (B,N,D) f32
    const int*   eidx = (const int*)d_in[1];     // (B,C,E,2) i32
    const float* wa   = (const float*)d_in[2];   // (C,2D,1) f32
    float* out = (float*)d_out;

    int*    cnt    = (int*)d_ws;                          // BC*N
    int*    rs     = cnt + BC_ * N_;                      // BC*(N+1)
    int*    head   = rs + BC_ * (N_ + 1);                 // BC*N
    float2* y      = (float2*)(head + BC_ * N_);          // BC*N float2
    float*  denom  = (float*)(y + BC_ * N_);              // BC*N
    int*    csr_i1 = (int*)(denom + BC_ * N_);            // BC*E
    float*  csr_ee = (float*)(csr_i1 + (size_t)BC_ * E_); // BC*E

    hipMemsetAsync(cnt, 0, (size_t)BC_ * N_ * sizeof(int), stream);

    gat_y      <<<BC_ * 40,  256, 0, stream>>>(x, wa, y);
    gat_hist   <<<BC_ * 625, 256, 0, stream>>>(eidx, cnt);
    gat_scan   <<<BC_,       256, 0, stream>>>(cnt, rs, head);
    gat_scatter<<<BC_ * 625, 256, 0, stream>>>(eidx, y, head, csr_i1, csr_ee);
    gat_denom  <<<(BC_ * N_ + 255) / 256, 256, 0, stream>>>(rs, csr_ee, denom);
    gat_acc    <<<B_ * N_ / 4, 256, 0, stream>>>(x, rs, csr_i1, csr_ee, denom, out);
}

// Round 3
// 266.546 us; speedup vs baseline: 1.6520x; 1.3478x over previous
//
#include <hip/hip_runtime.h>

#define B_ 4
#define N_ 10000
#define D_ 64
#define C_ 2
#define E_ 160000
#define BC_ (B_ * C_)
#define RSS_ (N_ + 4)          // row_start stride, padded for 16B alignment
#define EPS_ 1e-10f

// per-node dots: y1 = x·wa[c,0:64] (used when node is i1), y0 = x·wa[c,64:128] (i0)
__global__ void gat_y(const float* __restrict__ x, const float* __restrict__ wa,
                      float* __restrict__ y1, float* __restrict__ y0) {
    int bc = blockIdx.x / 40;
    int n  = (blockIdx.x % 40) * 256 + threadIdx.x;
    if (n >= N_) return;
    int b = bc / C_, c = bc % C_;
    const float4* xr = (const float4*)(x + ((size_t)b * N_ + n) * D_);
    const float4* w1 = (const float4*)(wa + (size_t)c * 2 * D_);
    const float4* w0 = w1 + D_ / 4;
    float a = 0.f, bb = 0.f;
#pragma unroll
    for (int i = 0; i < D_ / 4; ++i) {
        float4 xv = xr[i];
        float4 u = w1[i], v = w0[i];
        a  += xv.x * u.x + xv.y * u.y + xv.z * u.z + xv.w * u.w;
        bb += xv.x * v.x + xv.y * v.y + xv.z * v.z + xv.w * v.w;
    }
    y1[bc * N_ + n] = a;
    y0[bc * N_ + n] = bb;
}

__global__ void gat_hist(const int* __restrict__ eidx, int* __restrict__ cnt) {
    int bc = blockIdx.x / 625;
    int e  = (blockIdx.x % 625) * 256 + threadIdx.x;
    const int2* ep = (const int2*)eidx + (size_t)bc * E_;
    atomicAdd(&cnt[bc * N_ + ep[e].x], 1);
}

// local exclusive scan of 1024-element chunks (80 blocks), chunk totals -> partial
__global__ void gat_scanA(const int* __restrict__ cnt, int* __restrict__ rs,
                          int* __restrict__ partial) {
    int bc = blockIdx.x / 10, chunk = blockIdx.x % 10;
    int base = chunk * 1024 + threadIdx.x * 4;
    int4 v = make_int4(0, 0, 0, 0);
    if (base + 3 < N_) v = *(const int4*)(cnt + bc * N_ + base);
    int s4 = v.x + v.y + v.z + v.w;
    __shared__ int sd[256];
    sd[threadIdx.x] = s4;
    __syncthreads();
#pragma unroll
    for (int off = 1; off < 256; off <<= 1) {
        int t = (threadIdx.x >= off) ? sd[threadIdx.x - off] : 0;
        __syncthreads();
        sd[threadIdx.x] += t;
        __syncthreads();
    }
    int excl = sd[threadIdx.x] - s4;   // exclusive within chunk
    if (base + 3 < N_) {
        int4 o;
        o.x = excl; o.y = excl + v.x; o.z = o.y + v.y; o.w = o.z + v.z;
        *(int4*)(rs + bc * RSS_ + base) = o;
    }
    if (threadIdx.x == 255) partial[bc * 10 + chunk] = sd[255];
}

// add chunk offsets (each block sums its <=9 predecessors), emit rs + head
__global__ void gat_scanC(const int* __restrict__ partial, int* __restrict__ rs,
                          int* __restrict__ head) {
    int bc = blockIdx.x / 10, chunk = blockIdx.x % 10;
    int off = 0;
    for (int k = 0; k < chunk; ++k) off += partial[bc * 10 + k];
    int base = chunk * 1024 + threadIdx.x * 4;
    if (base + 3 < N_) {
        int4 v = *(int4*)(rs + bc * RSS_ + base);
        v.x += off; v.y += off; v.z += off; v.w += off;
        *(int4*)(rs + bc * RSS_ + base) = v;
        *(int4*)(head + bc * N_ + base) = v;
    }
    if (chunk == 9 && threadIdx.x == 0) rs[bc * RSS_ + N_] = E_;
}

// per edge: ev = exp(leaky_relu(y1[i1]+y0[i0])); csr[pos] = {i1, ev}
__global__ void gat_scatter(const int* __restrict__ eidx, const float* __restrict__ y1,
                            const float* __restrict__ y0, int* __restrict__ head,
                            int2* __restrict__ csr) {
    int bc = blockIdx.x / 625;
    int e  = (blockIdx.x % 625) * 256 + threadIdx.x;
    const int2* ep = (const int2*)eidx + (size_t)bc * E_;
    int2 ii = ep[e];                       // x = i0 (dst), y = i1 (src)
    float s  = y1[bc * N_ + ii.y] + y0[bc * N_ + ii.x];
    float lr = s > 0.f ? s : 0.2f * s;
    float ev = __expf(lr);
    int pos = atomicAdd(&head[bc * N_ + ii.x], 1);
    csr[(size_t)bc * E_ + pos] = make_int2(ii.y, __float_as_int(ev));
}

// rd[bc,n] = 1 / (segment_sum(ev) + eps)
__global__ void gat_denom(const int* __restrict__ rs, const int2* __restrict__ csr,
                          float* __restrict__ rd) {
    int gid = blockIdx.x * 256 + threadIdx.x;
    if (gid >= BC_ * N_) return;
    int bc = gid / N_, n = gid % N_;
    int s = rs[bc * RSS_ + n], t = rs[bc * RSS_ + n + 1];
    const int2* cp = csr + (size_t)bc * E_;
    float sum = 0.f;
    for (int j = s; j < t; ++j) sum += __int_as_float(cp[j].y);
    rd[bc * N_ + n] = 1.f / (sum + EPS_);
}

// wave per (b,n,c); unroll x4; channels combined via LDS; one coalesced store
__global__ void gat_acc(const float* __restrict__ x, const int* __restrict__ rs,
                        const int2* __restrict__ csr, const float* __restrict__ rd,
                        float* __restrict__ out) {
    int lane = threadIdx.x & 63;
    int w    = threadIdx.x >> 6;               // 0..3
    int node = blockIdx.x * 2 + (w >> 1);      // 0..B*N-1
    int c    = w & 1;
    int b = node / N_, n = node % N_;
    int bc = b * C_ + c;
    const float* xb  = x + (size_t)b * N_ * D_;
    const int2*  cp  = csr + (size_t)bc * E_;
    const float* rdp = rd + bc * N_;
    int s = rs[bc * RSS_ + n], t = rs[bc * RSS_ + n + 1];
    float acc = 0.f;
    int j = s;
    for (; j + 4 <= t; j += 4) {
        int2 e0 = cp[j], e1 = cp[j + 1], e2 = cp[j + 2], e3 = cp[j + 3];
        float r0 = rdp[e0.x], r1 = rdp[e1.x], r2 = rdp[e2.x], r3 = rdp[e3.x];
        float x0 = xb[e0.x * D_ + lane], x1 = xb[e1.x * D_ + lane];
        float x2 = xb[e2.x * D_ + lane], x3 = xb[e3.x * D_ + lane];
        acc += __int_as_float(e0.y) * r0 * x0;
        acc += __int_as_float(e1.y) * r1 * x1;
        acc += __int_as_float(e2.y) * r2 * x2;
        acc += __int_as_float(e3.y) * r3 * x3;
    }
    for (; j < t; ++j) {
        int2 e = cp[j];
        acc += __int_as_float(e.y) * rdp[e.x] * xb[e.x * D_ + lane];
    }
    float sg = 1.f / (1.f + __expf(-acc));
    __shared__ float sh[2][64];
    if (c == 1) sh[w >> 1][lane] = sg;
    __syncthreads();
    if (c == 0) out[((size_t)b * N_ + n) * D_ + lane] = sg + sh[w >> 1][lane];
}

extern "C" void kernel_launch(void* const* d_in, const int* in_sizes, int n_in,
                              void* d_out, int out_size, void* d_ws, size_t ws_size,
                              hipStream_t stream) {
    const float* x    = (const float*)d_in[0];
    const int*   eidx = (const int*)d_in[1];
    const float* wa   = (const float*)d_in[2];
    float* out = (float*)d_out;

    int*   cnt     = (int*)d_ws;                       // BC*N
    int*   rs      = cnt + BC_ * N_;                   // BC*RSS
    int*   head    = rs + BC_ * RSS_;                  // BC*N
    int*   partial = head + BC_ * N_;                  // BC*10
    float* y1      = (float*)(partial + BC_ * 16);     // BC*N
    float* y0      = y1 + BC_ * N_;                    // BC*N
    float* rd      = y0 + BC_ * N_;                    // BC*N
    int2*  csr     = (int2*)(rd + BC_ * N_);           // BC*E int2

    hipMemsetAsync(cnt, 0, (size_t)BC_ * N_ * sizeof(int), stream);

    gat_y      <<<BC_ * 40,  256, 0, stream>>>(x, wa, y1, y0);
    gat_hist   <<<BC_ * 625, 256, 0, stream>>>(eidx, cnt);
    gat_scanA  <<<BC_ * 10,  256, 0, stream>>>(cnt, rs, partial);
    gat_scanC  <<<BC_ * 10,  256, 0, stream>>>(partial, rs, head);
    gat_scatter<<<BC_ * 625, 256, 0, stream>>>(eidx, y1, y0, head, csr);
    gat_denom  <<<(BC_ * N_ + 255) / 256, 256, 0, stream>>>(rs, csr, rd);
    gat_acc    <<<B_ * N_ / 2, 256, 0, stream>>>(x, rs, csr, rd, out);
}

// Round 4
// 243.669 us; speedup vs baseline: 1.8071x; 1.0939x over previous
//
#include <hip/hip_runtime.h>

#define B_ 4
#define N_ 10000
#define D_ 64
#define C_ 2
#define E_ 160000
#define BC_ (B_ * C_)
#define RSS_ (N_ + 4)          // row_start stride, padded for 16B alignment
#define EPS_ 1e-10f

// per-node dots: y1 = x·wa[c,0:64] (node as i1), y0 = x·wa[c,64:128] (node as i0)
__global__ void gat_y(const float* __restrict__ x, const float* __restrict__ wa,
                      float* __restrict__ y1, float* __restrict__ y0) {
    int bc = blockIdx.x & 7;
    int n  = (blockIdx.x >> 3) * 256 + threadIdx.x;   // 40 chunks
    if (n >= N_) return;
    int b = bc / C_, c = bc % C_;
    const float4* xr = (const float4*)(x + ((size_t)b * N_ + n) * D_);
    const float4* w1 = (const float4*)(wa + (size_t)c * 2 * D_);
    const float4* w0 = w1 + D_ / 4;
    float a = 0.f, bb = 0.f;
#pragma unroll
    for (int i = 0; i < D_ / 4; ++i) {
        float4 xv = xr[i];
        float4 u = w1[i], v = w0[i];
        a  += xv.x * u.x + xv.y * u.y + xv.z * u.z + xv.w * u.w;
        bb += xv.x * v.x + xv.y * v.y + xv.z * v.z + xv.w * v.w;
    }
    y1[bc * N_ + n] = a;
    y0[bc * N_ + n] = bb;
}

// histogram of destination i0 per (b,c); bc XCD-local via &7 swizzle
__global__ void gat_hist(const int* __restrict__ eidx, int* __restrict__ cnt) {
    int bc = blockIdx.x & 7;
    int e  = (blockIdx.x >> 3) * 256 + threadIdx.x;    // 625 chunks
    const int2* ep = (const int2*)eidx + (size_t)bc * E_;
    atomicAdd(&cnt[bc * N_ + ep[e].x], 1);
}

// local exclusive scan of 1024-element chunks (80 blocks), chunk totals -> partial
__global__ void gat_scanA(const int* __restrict__ cnt, int* __restrict__ rs,
                          int* __restrict__ partial) {
    int bc = blockIdx.x & 7, chunk = blockIdx.x >> 3;  // 10 chunks
    int base = chunk * 1024 + threadIdx.x * 4;
    int4 v = make_int4(0, 0, 0, 0);
    if (base + 3 < N_) v = *(const int4*)(cnt + bc * N_ + base);
    int s4 = v.x + v.y + v.z + v.w;
    __shared__ int sd[256];
    sd[threadIdx.x] = s4;
    __syncthreads();
#pragma unroll
    for (int off = 1; off < 256; off <<= 1) {
        int t = (threadIdx.x >= off) ? sd[threadIdx.x - off] : 0;
        __syncthreads();
        sd[threadIdx.x] += t;
        __syncthreads();
    }
    int excl = sd[threadIdx.x] - s4;
    if (base + 3 < N_) {
        int4 o;
        o.x = excl; o.y = excl + v.x; o.z = o.y + v.y; o.w = o.z + v.z;
        *(int4*)(rs + bc * RSS_ + base) = o;
    }
    if (threadIdx.x == 255) partial[bc * 10 + chunk] = sd[255];
}

// add chunk offsets, emit rs + head
__global__ void gat_scanC(const int* __restrict__ partial, int* __restrict__ rs,
                          int* __restrict__ head) {
    int bc = blockIdx.x & 7, chunk = blockIdx.x >> 3;
    int off = 0;
    for (int k = 0; k < chunk; ++k) off += partial[bc * 10 + k];
    int base = chunk * 1024 + threadIdx.x * 4;
    if (base + 3 < N_) {
        int4 v = *(int4*)(rs + bc * RSS_ + base);
        v.x += off; v.y += off; v.z += off; v.w += off;
        *(int4*)(rs + bc * RSS_ + base) = v;
        *(int4*)(head + bc * N_ + base) = v;
    }
    if (chunk == 9 && threadIdx.x == 0) rs[bc * RSS_ + N_] = E_;
}

// counting-sort placement: only i1 (2 bytes) is scattered
__global__ void gat_scatter(const int* __restrict__ eidx, int* __restrict__ head,
                            unsigned short* __restrict__ csr_i1) {
    int bc = blockIdx.x & 7;
    int e  = (blockIdx.x >> 3) * 256 + threadIdx.x;
    const int2* ep = (const int2*)eidx + (size_t)bc * E_;
    int2 ii = ep[e];                       // x = i0 (dst), y = i1 (src)
    int pos = atomicAdd(&head[bc * N_ + ii.x], 1);
    csr_i1[(size_t)bc * E_ + pos] = (unsigned short)ii.y;
}

// per node: recompute ev per edge (y1[i1] + y0[n]), write ee sequentially,
// rd[n] = 1/(sum+eps)
__global__ void gat_denom(const int* __restrict__ rs, const unsigned short* __restrict__ csr_i1,
                          const float* __restrict__ y1, const float* __restrict__ y0,
                          float* __restrict__ csr_ee, float* __restrict__ rd) {
    int bc = blockIdx.x & 7;
    int n  = (blockIdx.x >> 3) * 256 + threadIdx.x;    // 40 chunks
    if (n >= N_) return;
    int s = rs[bc * RSS_ + n], t = rs[bc * RSS_ + n + 1];
    const unsigned short* ip = csr_i1 + (size_t)bc * E_;
    const float* y1p = y1 + bc * N_;
    float* eep = csr_ee + (size_t)bc * E_;
    float y0n = y0[bc * N_ + n];
    float sum = 0.f;
    int j = s;
    for (; j + 4 <= t; j += 4) {
        int a0 = ip[j], a1 = ip[j + 1], a2 = ip[j + 2], a3 = ip[j + 3];
        float s0 = y1p[a0] + y0n, s1 = y1p[a1] + y0n;
        float s2 = y1p[a2] + y0n, s3 = y1p[a3] + y0n;
        float e0 = __expf(s0 > 0.f ? s0 : 0.2f * s0);
        float e1 = __expf(s1 > 0.f ? s1 : 0.2f * s1);
        float e2 = __expf(s2 > 0.f ? s2 : 0.2f * s2);
        float e3 = __expf(s3 > 0.f ? s3 : 0.2f * s3);
        eep[j] = e0; eep[j + 1] = e1; eep[j + 2] = e2; eep[j + 3] = e3;
        sum += e0 + e1 + e2 + e3;
    }
    for (; j < t; ++j) {
        int a = ip[j];
        float sc = y1p[a] + y0n;
        float ev = __expf(sc > 0.f ? sc : 0.2f * sc);
        eep[j] = ev;
        sum += ev;
    }
    rd[bc * N_ + n] = 1.f / (sum + EPS_);
}

// wave per (b,n,c); seq i1+ev, hot rd gather, x row gather; unroll x4
__global__ void gat_acc(const float* __restrict__ x, const int* __restrict__ rs,
                        const unsigned short* __restrict__ csr_i1,
                        const float* __restrict__ csr_ee, const float* __restrict__ rd,
                        float* __restrict__ out) {
    int lane = threadIdx.x & 63;
    int w    = threadIdx.x >> 6;               // 0..3
    int b    = blockIdx.x & 3;                 // batch XCD-affine
    int nn   = blockIdx.x >> 2;                // 0..4999
    int n    = nn * 2 + (w >> 1);
    int c    = w & 1;
    int bc = b * C_ + c;
    const float* xb  = x + (size_t)b * N_ * D_;
    const unsigned short* ip = csr_i1 + (size_t)bc * E_;
    const float* eep = csr_ee + (size_t)bc * E_;
    const float* rdp = rd + bc * N_;
    int s = rs[bc * RSS_ + n], t = rs[bc * RSS_ + n + 1];
    float acc = 0.f;
    int j = s;
    for (; j + 4 <= t; j += 4) {
        int a0 = ip[j], a1 = ip[j + 1], a2 = ip[j + 2], a3 = ip[j + 3];
        float e0 = eep[j], e1 = eep[j + 1], e2 = eep[j + 2], e3 = eep[j + 3];
        float r0 = rdp[a0], r1 = rdp[a1], r2 = rdp[a2], r3 = rdp[a3];
        float x0 = xb[a0 * D_ + lane], x1 = xb[a1 * D_ + lane];
        float x2 = xb[a2 * D_ + lane], x3 = xb[a3 * D_ + lane];
        acc += e0 * r0 * x0;
        acc += e1 * r1 * x1;
        acc += e2 * r2 * x2;
        acc += e3 * r3 * x3;
    }
    for (; j < t; ++j) {
        int a = ip[j];
        acc += eep[j] * rdp[a] * xb[a * D_ + lane];
    }
    float sg = 1.f / (1.f + __expf(-acc));
    __shared__ float sh[2][64];
    if (c == 1) sh[w >> 1][lane] = sg;
    __syncthreads();
    if (c == 0) out[((size_t)b * N_ + n) * D_ + lane] = sg + sh[w >> 1][lane];
}

extern "C" void kernel_launch(void* const* d_in, const int* in_sizes, int n_in,
                              void* d_out, int out_size, void* d_ws, size_t ws_size,
                              hipStream_t stream) {
    const float* x    = (const float*)d_in[0];
    const int*   eidx = (const int*)d_in[1];
    const float* wa   = (const float*)d_in[2];
    float* out = (float*)d_out;

    int*   cnt     = (int*)d_ws;                           // BC*N
    int*   rs      = cnt + BC_ * N_;                       // BC*RSS
    int*   head    = rs + BC_ * RSS_;                      // BC*N
    int*   partial = head + BC_ * N_;                      // BC*16
    float* y1      = (float*)(partial + BC_ * 16);         // BC*N
    float* y0      = y1 + BC_ * N_;                        // BC*N
    float* rd      = y0 + BC_ * N_;                        // BC*N
    float* csr_ee  = rd + BC_ * N_;                        // BC*E
    unsigned short* csr_i1 = (unsigned short*)(csr_ee + (size_t)BC_ * E_); // BC*E u16

    hipMemsetAsync(cnt, 0, (size_t)BC_ * N_ * sizeof(int), stream);

    gat_y      <<<BC_ * 40,  256, 0, stream>>>(x, wa, y1, y0);
    gat_hist   <<<BC_ * 625, 256, 0, stream>>>(eidx, cnt);
    gat_scanA  <<<BC_ * 10,  256, 0, stream>>>(cnt, rs, partial);
    gat_scanC  <<<BC_ * 10,  256, 0, stream>>>(partial, rs, head);
    gat_scatter<<<BC_ * 625, 256, 0, stream>>>(eidx, head, csr_i1);
    gat_denom  <<<BC_ * 40,  256, 0, stream>>>(rs, csr_i1, y1, y0, csr_ee, rd);
    gat_acc    <<<B_ * N_ / 2, 256, 0, stream>>>(x, rs, csr_i1, csr_ee, rd, out);
}

// Round 5
// 236.780 us; speedup vs baseline: 1.8597x; 1.0291x over previous
//
#include <hip/hip_runtime.h>

#define B_ 4
#define N_ 10000
#define D_ 64
#define C_ 2
#define E_ 160000
#define BC_ (B_ * C_)
#define RSS_ (N_ + 4)          // row_start stride, padded for 16B alignment
#define EPS_ 1e-10f

// per-node dots: y1 = x·wa[c,0:64] (node as i1), y0 = x·wa[c,64:128] (node as i0)
__global__ void gat_y(const float* __restrict__ x, const float* __restrict__ wa,
                      float* __restrict__ y1, float* __restrict__ y0) {
    int bc = blockIdx.x & 7;
    int n  = (blockIdx.x >> 3) * 256 + threadIdx.x;   // 40 chunks
    if (n >= N_) return;
    int b = bc / C_, c = bc % C_;
    const float4* xr = (const float4*)(x + ((size_t)b * N_ + n) * D_);
    const float4* w1 = (const float4*)(wa + (size_t)c * 2 * D_);
    const float4* w0 = w1 + D_ / 4;
    float a = 0.f, bb = 0.f;
#pragma unroll
    for (int i = 0; i < D_ / 4; ++i) {
        float4 xv = xr[i];
        float4 u = w1[i], v = w0[i];
        a  += xv.x * u.x + xv.y * u.y + xv.z * u.z + xv.w * u.w;
        bb += xv.x * v.x + xv.y * v.y + xv.z * v.z + xv.w * v.w;
    }
    y1[bc * N_ + n] = a;
    y0[bc * N_ + n] = bb;
}

// histogram of destination i0 per (b,c); bc XCD-local via &7 swizzle
__global__ void gat_hist(const int* __restrict__ eidx, int* __restrict__ cnt) {
    int bc = blockIdx.x & 7;
    int e  = (blockIdx.x >> 3) * 256 + threadIdx.x;    // 625 chunks
    const int2* ep = (const int2*)eidx + (size_t)bc * E_;
    atomicAdd(&cnt[bc * N_ + ep[e].x], 1);
}

// local exclusive scan of 1024-element chunks (80 blocks), chunk totals -> partial
__global__ void gat_scanA(const int* __restrict__ cnt, int* __restrict__ rs,
                          int* __restrict__ partial) {
    int bc = blockIdx.x & 7, chunk = blockIdx.x >> 3;  // 10 chunks
    int base = chunk * 1024 + threadIdx.x * 4;
    int4 v = make_int4(0, 0, 0, 0);
    if (base + 3 < N_) v = *(const int4*)(cnt + bc * N_ + base);
    int s4 = v.x + v.y + v.z + v.w;
    __shared__ int sd[256];
    sd[threadIdx.x] = s4;
    __syncthreads();
#pragma unroll
    for (int off = 1; off < 256; off <<= 1) {
        int t = (threadIdx.x >= off) ? sd[threadIdx.x - off] : 0;
        __syncthreads();
        sd[threadIdx.x] += t;
        __syncthreads();
    }
    int excl = sd[threadIdx.x] - s4;
    if (base + 3 < N_) {
        int4 o;
        o.x = excl; o.y = excl + v.x; o.z = o.y + v.y; o.w = o.z + v.z;
        *(int4*)(rs + bc * RSS_ + base) = o;
    }
    if (threadIdx.x == 255) partial[bc * 10 + chunk] = sd[255];
}

// add chunk offsets, emit rs + head
__global__ void gat_scanC(const int* __restrict__ partial, int* __restrict__ rs,
                          int* __restrict__ head) {
    int bc = blockIdx.x & 7, chunk = blockIdx.x >> 3;
    int off = 0;
    for (int k = 0; k < chunk; ++k) off += partial[bc * 10 + k];
    int base = chunk * 1024 + threadIdx.x * 4;
    if (base + 3 < N_) {
        int4 v = *(int4*)(rs + bc * RSS_ + base);
        v.x += off; v.y += off; v.z += off; v.w += off;
        *(int4*)(rs + bc * RSS_ + base) = v;
        *(int4*)(head + bc * N_ + base) = v;
    }
    if (chunk == 9 && threadIdx.x == 0) rs[bc * RSS_ + N_] = E_;
}

// counting-sort placement: only i1 (2 bytes) is scattered
__global__ void gat_scatter(const int* __restrict__ eidx, int* __restrict__ head,
                            unsigned short* __restrict__ csr_i1) {
    int bc = blockIdx.x & 7;
    int e  = (blockIdx.x >> 3) * 256 + threadIdx.x;
    const int2* ep = (const int2*)eidx + (size_t)bc * E_;
    int2 ii = ep[e];                       // x = i0 (dst), y = i1 (src)
    int pos = atomicAdd(&head[bc * N_ + ii.x], 1);
    csr_i1[(size_t)bc * E_ + pos] = (unsigned short)ii.y;
}

// wave per (bc,n): lane j handles edge j — lane-parallel exp + coalesced ee store,
// shfl_xor reduce -> rd[n] = 1/(sum+eps)
__global__ void gat_denom(const int* __restrict__ rs, const unsigned short* __restrict__ csr_i1,
                          const float* __restrict__ y1, const float* __restrict__ y0,
                          float* __restrict__ csr_ee, float* __restrict__ rd) {
    int lane = threadIdx.x & 63;
    int w    = threadIdx.x >> 6;           // 0..3
    int bc   = blockIdx.x & 7;
    int n    = (blockIdx.x >> 3) * 4 + w;  // 2500 chunks * 4 waves
    const unsigned short* ip = csr_i1 + (size_t)bc * E_;
    const float* y1p = y1 + bc * N_;
    float* eep = csr_ee + (size_t)bc * E_;
    int s = rs[bc * RSS_ + n], t = rs[bc * RSS_ + n + 1];
    float y0n = y0[bc * N_ + n];
    float sum = 0.f;
    for (int base = s; base < t; base += 64) {
        int m = t - base; if (m > 64) m = 64;
        float ev = 0.f;
        if (lane < m) {
            int a = ip[base + lane];
            float sc = y1p[a] + y0n;
            ev = __expf(sc > 0.f ? sc : 0.2f * sc);
            eep[base + lane] = ev;
        }
        sum += ev;
    }
#pragma unroll
    for (int off = 32; off > 0; off >>= 1) sum += __shfl_xor(sum, off);
    if (lane == 0) rd[bc * N_ + n] = 1.f / (sum + EPS_);
}

// wave per (b,n,c): lane-parallel metadata (w_j = ev_j * rd[a_j]), then per-edge
// readlane-broadcast + x-row load + fma, unrolled x4 with zero padding
__global__ void gat_acc(const float* __restrict__ x, const int* __restrict__ rs,
                        const unsigned short* __restrict__ csr_i1,
                        const float* __restrict__ csr_ee, const float* __restrict__ rd,
                        float* __restrict__ out) {
    int lane = threadIdx.x & 63;
    int w    = threadIdx.x >> 6;               // 0..3
    int b    = blockIdx.x & 3;                 // batch XCD-affine
    int nn   = blockIdx.x >> 2;                // 0..4999
    int n    = nn * 2 + (w >> 1);
    int c    = w & 1;
    int bc = b * C_ + c;
    const float* xb  = x + (size_t)b * N_ * D_ + lane;
    const unsigned short* ip = csr_i1 + (size_t)bc * E_;
    const float* eep = csr_ee + (size_t)bc * E_;
    const float* rdp = rd + bc * N_;
    int s = rs[bc * RSS_ + n], t = rs[bc * RSS_ + n + 1];
    float acc = 0.f;
    for (int base = s; base < t; base += 64) {
        int m = t - base; if (m > 64) m = 64;
        int a = 0; float wgt = 0.f;
        if (lane < m) {
            a   = ip[base + lane];             // coalesced u16
            wgt = eep[base + lane] * rdp[a];   // coalesced + hot gather, once per edge
        }
        int mp = (m + 3) & ~3;
        for (int j = 0; j < mp; j += 4) {
            int   a0 = __shfl(a, j),     a1 = __shfl(a, j + 1);
            int   a2 = __shfl(a, j + 2), a3 = __shfl(a, j + 3);
            float w0 = __shfl(wgt, j),     w1 = __shfl(wgt, j + 1);
            float w2 = __shfl(wgt, j + 2), w3 = __shfl(wgt, j + 3);
            float x0 = xb[a0 * D_], x1 = xb[a1 * D_];
            float x2 = xb[a2 * D_], x3 = xb[a3 * D_];
            acc += w0 * x0;
            acc += w1 * x1;
            acc += w2 * x2;
            acc += w3 * x3;
        }
    }
    float sg = 1.f / (1.f + __expf(-acc));
    __shared__ float sh[2][64];
    if (c == 1) sh[w >> 1][lane] = sg;
    __syncthreads();
    if (c == 0) out[((size_t)b * N_ + n) * D_ + lane] = sg + sh[w >> 1][lane];
}

extern "C" void kernel_launch(void* const* d_in, const int* in_sizes, int n_in,
                              void* d_out, int out_size, void* d_ws, size_t ws_size,
                              hipStream_t stream) {
    const float* x    = (const float*)d_in[0];
    const int*   eidx = (const int*)d_in[1];
    const float* wa   = (const float*)d_in[2];
    float* out = (float*)d_out;

    int*   cnt     = (int*)d_ws;                           // BC*N
    int*   rs      = cnt + BC_ * N_;                       // BC*RSS
    int*   head    = rs + BC_ * RSS_;                      // BC*N
    int*   partial = head + BC_ * N_;                      // BC*16
    float* y1      = (float*)(partial + BC_ * 16);         // BC*N
    float* y0      = y1 + BC_ * N_;                        // BC*N
    float* rd      = y0 + BC_ * N_;                        // BC*N
    float* csr_ee  = rd + BC_ * N_;                        // BC*E
    unsigned short* csr_i1 = (unsigned short*)(csr_ee + (size_t)BC_ * E_); // BC*E u16

    hipMemsetAsync(cnt, 0, (size_t)BC_ * N_ * sizeof(int), stream);

    gat_y      <<<BC_ * 40,   256, 0, stream>>>(x, wa, y1, y0);
    gat_hist   <<<BC_ * 625,  256, 0, stream>>>(eidx, cnt);
    gat_scanA  <<<BC_ * 10,   256, 0, stream>>>(cnt, rs, partial);
    gat_scanC  <<<BC_ * 10,   256, 0, stream>>>(partial, rs, head);
    gat_scatter<<<BC_ * 625,  256, 0, stream>>>(eidx, head, csr_i1);
    gat_denom  <<<BC_ * 2500, 256, 0, stream>>>(rs, csr_i1, y1, y0, csr_ee, rd);
    gat_acc    <<<B_ * N_ / 2, 256, 0, stream>>>(x, rs, csr_i1, csr_ee, rd, out);
}

// Round 6
// 142.845 us; speedup vs baseline: 3.0827x; 1.6576x over previous
//
#include <hip/hip_runtime.h>

#define B_ 4
#define N_ 10000
#define D_ 64
#define C_ 2
#define E_ 160000
#define BC_ (B_ * C_)
#define G_ 40                   // coarse buckets of 256 nodes (i0 >> 8)
#define CAP_ 5120               // slots per (bc,bucket); mean 4096, +16 sigma
#define NBLK_ 25                // bucket-pass blocks per bc (6400 edges each)
#define EPB_ 6400
#define EPS_ 1e-10f

// per-node dots: y1 = x·wa[c,0:64] (node as i1), y0 = x·wa[c,64:128] (node as i0)
__global__ void gat_y(const float* __restrict__ x, const float* __restrict__ wa,
                      float* __restrict__ y1, float* __restrict__ y0) {
    int bc = blockIdx.x & 7;
    int n  = (blockIdx.x >> 3) * 256 + threadIdx.x;   // 40 chunks
    if (n >= N_) return;
    int b = bc / C_, c = bc % C_;
    const float4* xr = (const float4*)(x + ((size_t)b * N_ + n) * D_);
    const float4* w1 = (const float4*)(wa + (size_t)c * 2 * D_);
    const float4* w0 = w1 + D_ / 4;
    float a = 0.f, bb = 0.f;
#pragma unroll
    for (int i = 0; i < D_ / 4; ++i) {
        float4 xv = xr[i];
        float4 u = w1[i], v = w0[i];
        a  += xv.x * u.x + xv.y * u.y + xv.z * u.z + xv.w * u.w;
        bb += xv.x * v.x + xv.y * v.y + xv.z * v.z + xv.w * v.w;
    }
    y1[bc * N_ + n] = a;
    y0[bc * N_ + n] = bb;
}

// coarse bucket pass: per-block LDS histogram -> one global atomic per
// (block,bucket) chunk reservation -> dense chunk writes of packed edges
__global__ void gat_bucket(const int* __restrict__ eidx, int* __restrict__ gcount,
                           unsigned int* __restrict__ bpack) {
    int bc  = blockIdx.x & 7;
    int blk = blockIdx.x >> 3;              // 0..24
    const int2* ep = (const int2*)eidx + (size_t)bc * E_ + (size_t)blk * EPB_;
    __shared__ int hist[G_];
    __shared__ int cur[G_];
    if (threadIdx.x < G_) hist[threadIdx.x] = 0;
    __syncthreads();
    int2 ev[25];
#pragma unroll
    for (int k = 0; k < 25; ++k) {
        ev[k] = ep[k * 256 + threadIdx.x];
        atomicAdd(&hist[ev[k].x >> 8], 1);
    }
    __syncthreads();
    if (threadIdx.x < G_)
        cur[threadIdx.x] = atomicAdd(&gcount[bc * G_ + threadIdx.x], hist[threadIdx.x]);
    __syncthreads();
    unsigned int base = (unsigned int)bc * G_ * CAP_;
#pragma unroll
    for (int k = 0; k < 25; ++k) {
        int g   = ev[k].x >> 8;
        int off = atomicAdd(&cur[g], 1);
        bpack[base + g * CAP_ + off] =
            ((unsigned int)(ev[k].x & 255) << 16) | (unsigned int)ev[k].y;
    }
}

// fine pass: one block per (bc,bucket) — counting-sort 256 nodes in LDS,
// compute ee, per-node denom, write csr/rs/rd coalesced
__global__ void gat_fine(const unsigned int* __restrict__ bpack,
                         const int* __restrict__ gcount,
                         const float* __restrict__ y1, const float* __restrict__ y0,
                         unsigned short* __restrict__ csr_i1, float* __restrict__ csr_ee,
                         int* __restrict__ rs_s, int* __restrict__ rs_e,
                         float* __restrict__ rd) {
    int bc = blockIdx.x & 7;
    int g  = blockIdx.x >> 3;               // 0..39
    int K  = gcount[bc * G_ + g];
    int R  = bc * G_ * CAP_ + g * CAP_;     // absolute csr base for this bucket
    const unsigned int* bp = bpack + R;
    const float* y1p = y1 + bc * N_;

    __shared__ int   cnt[256], excl[256], cur[256];
    __shared__ float y0l[256];
    __shared__ unsigned short li1[CAP_];
    __shared__ float lee[CAP_];
    __shared__ int sd[256];

    int node = g * 256 + threadIdx.x;
    cnt[threadIdx.x] = 0;
    y0l[threadIdx.x] = (node < N_) ? y0[bc * N_ + node] : 0.f;
    __syncthreads();

    for (int j = threadIdx.x; j < K; j += 256)
        atomicAdd(&cnt[bp[j] >> 16], 1);
    __syncthreads();

    // exclusive scan of cnt[256]
    int v = cnt[threadIdx.x];
    sd[threadIdx.x] = v;
    __syncthreads();
#pragma unroll
    for (int off = 1; off < 256; off <<= 1) {
        int t = (threadIdx.x >= off) ? sd[threadIdx.x - off] : 0;
        __syncthreads();
        sd[threadIdx.x] += t;
        __syncthreads();
    }
    int ex = sd[threadIdx.x] - v;
    excl[threadIdx.x] = ex;
    cur[threadIdx.x]  = ex;
    if (node < N_) {
        rs_s[bc * N_ + node] = R + ex;
        rs_e[bc * N_ + node] = R + ex + v;
    }
    __syncthreads();

    for (int j = threadIdx.x; j < K; j += 256) {
        unsigned int p = bp[j];
        int ln = p >> 16;
        int i1 = p & 0xffff;
        int slot = atomicAdd(&cur[ln], 1);
        li1[slot] = (unsigned short)i1;
        float sc = y1p[i1] + y0l[ln];
        lee[slot] = __expf(sc > 0.f ? sc : 0.2f * sc);
    }
    __syncthreads();

    if (node < N_) {
        int s = excl[threadIdx.x], t = s + v;
        float sum = 0.f;
        for (int j = s; j < t; ++j) sum += lee[j];
        rd[bc * N_ + node] = 1.f / (sum + EPS_);
    }
    for (int j = threadIdx.x; j < K; j += 256) {
        csr_i1[R + j] = li1[j];
        csr_ee[R + j] = lee[j];
    }
}

// wave per (b,n,c): lane-parallel metadata (w_j = ev_j * rd[a_j]), then per-edge
// shfl-broadcast + x-row load + fma, unrolled x4 with zero padding
__global__ void gat_acc(const float* __restrict__ x, const int* __restrict__ rs_s,
                        const int* __restrict__ rs_e,
                        const unsigned short* __restrict__ csr_i1,
                        const float* __restrict__ csr_ee, const float* __restrict__ rd,
                        float* __restrict__ out) {
    int lane = threadIdx.x & 63;
    int w    = threadIdx.x >> 6;               // 0..3
    int b    = blockIdx.x & 3;                 // batch XCD-affine
    int nn   = blockIdx.x >> 2;                // 0..4999
    int n    = nn * 2 + (w >> 1);
    int c    = w & 1;
    int bc = b * C_ + c;
    const float* xb  = x + (size_t)b * N_ * D_ + lane;
    const float* rdp = rd + bc * N_;
    int s = rs_s[bc * N_ + n], t = rs_e[bc * N_ + n];
    float acc = 0.f;
    for (int base = s; base < t; base += 64) {
        int m = t - base; if (m > 64) m = 64;
        int a = 0; float wgt = 0.f;
        if (lane < m) {
            a   = csr_i1[base + lane];             // coalesced u16
            wgt = csr_ee[base + lane] * rdp[a];    // coalesced + hot gather
        }
        int mp = (m + 3) & ~3;
        for (int j = 0; j < mp; j += 4) {
            int   a0 = __shfl(a, j),     a1 = __shfl(a, j + 1);
            int   a2 = __shfl(a, j + 2), a3 = __shfl(a, j + 3);
            float w0 = __shfl(wgt, j),     w1 = __shfl(wgt, j + 1);
            float w2 = __shfl(wgt, j + 2), w3 = __shfl(wgt, j + 3);
            float x0 = xb[a0 * D_], x1 = xb[a1 * D_];
            float x2 = xb[a2 * D_], x3 = xb[a3 * D_];
            acc += w0 * x0;
            acc += w1 * x1;
            acc += w2 * x2;
            acc += w3 * x3;
        }
    }
    float sg = 1.f / (1.f + __expf(-acc));
    __shared__ float sh[2][64];
    if (c == 1) sh[w >> 1][lane] = sg;
    __syncthreads();
    if (c == 0) out[((size_t)b * N_ + n) * D_ + lane] = sg + sh[w >> 1][lane];
}

extern "C" void kernel_launch(void* const* d_in, const int* in_sizes, int n_in,
                              void* d_out, int out_size, void* d_ws, size_t ws_size,
                              hipStream_t stream) {
    const float* x    = (const float*)d_in[0];
    const int*   eidx = (const int*)d_in[1];
    const float* wa   = (const float*)d_in[2];
    float* out = (float*)d_out;

    int*   gcount = (int*)d_ws;                                  // BC*G (pad 512)
    float* y1     = (float*)d_ws + 512;                          // BC*N
    float* y0     = y1 + BC_ * N_;                               // BC*N
    float* rd     = y0 + BC_ * N_;                               // BC*N
    int*   rs_s   = (int*)(rd + BC_ * N_);                       // BC*N
    int*   rs_e   = rs_s + BC_ * N_;                             // BC*N
    unsigned int* bpack  = (unsigned int*)(rs_e + BC_ * N_);     // BC*G*CAP
    float*        csr_ee = (float*)(bpack + (size_t)BC_ * G_ * CAP_); // BC*G*CAP
    unsigned short* csr_i1 = (unsigned short*)(csr_ee + (size_t)BC_ * G_ * CAP_);

    hipMemsetAsync(gcount, 0, BC_ * G_ * sizeof(int), stream);

    gat_y     <<<BC_ * 40,    256, 0, stream>>>(x, wa, y1, y0);
    gat_bucket<<<BC_ * NBLK_, 256, 0, stream>>>(eidx, gcount, bpack);
    gat_fine  <<<BC_ * G_,    256, 0, stream>>>(bpack, gcount, y1, y0,
                                                csr_i1, csr_ee, rs_s, rs_e, rd);
    gat_acc   <<<B_ * N_ / 2, 256, 0, stream>>>(x, rs_s, rs_e, csr_i1, csr_ee, rd, out);
}

// Round 7
// 137.811 us; speedup vs baseline: 3.1953x; 1.0365x over previous
//
#include <hip/hip_runtime.h>

#define B_ 4
#define N_ 10000
#define D_ 64
#define C_ 2
#define E_ 160000
#define BC_ (B_ * C_)
#define SH2_ 7                  // 128 nodes per fine bucket
#define NB2_ 128
#define G2_ 79                  // ceil(10000/128)
#define CAPF_ 2560              // slots per (bc,bucket); mean 2048, +11 sigma
#define NBLK_ 125               // bucket-pass blocks per bc
#define EPT_ 5                  // edges per thread in bucket pass
#define EPB_ (256 * EPT_)       // 1280 edges per block
#define EPS_ 1e-10f

// per-node dots: y1 = x·wa[c,0:64] (node as i1), y0 = x·wa[c,64:128] (node as i0)
__global__ void gat_y(const float* __restrict__ x, const float* __restrict__ wa,
                      float* __restrict__ y1, float* __restrict__ y0) {
    int bc = blockIdx.x & 7;
    int n  = (blockIdx.x >> 3) * 256 + threadIdx.x;   // 40 chunks
    if (n >= N_) return;
    int b = bc / C_, c = bc % C_;
    const float4* xr = (const float4*)(x + ((size_t)b * N_ + n) * D_);
    const float4* w1 = (const float4*)(wa + (size_t)c * 2 * D_);
    const float4* w0 = w1 + D_ / 4;
    float a = 0.f, bb = 0.f;
#pragma unroll
    for (int i = 0; i < D_ / 4; ++i) {
        float4 xv = xr[i];
        float4 u = w1[i], v = w0[i];
        a  += xv.x * u.x + xv.y * u.y + xv.z * u.z + xv.w * u.w;
        bb += xv.x * v.x + xv.y * v.y + xv.z * v.z + xv.w * v.w;
    }
    y1[bc * N_ + n] = a;
    y0[bc * N_ + n] = bb;
}

// coarse bucket pass: per-block LDS histogram -> one global atomic per
// (block,bucket) chunk reservation -> dense chunk writes of packed edges
__global__ void gat_bucket(const int* __restrict__ eidx, int* __restrict__ gcount,
                           unsigned int* __restrict__ bpack) {
    int bc  = blockIdx.x & 7;
    int blk = blockIdx.x >> 3;              // 0..124
    const int2* ep = (const int2*)eidx + (size_t)bc * E_ + (size_t)blk * EPB_;
    __shared__ int hist[G2_];
    __shared__ int cur[G2_];
    if (threadIdx.x < G2_) hist[threadIdx.x] = 0;
    __syncthreads();
    int2 ev[EPT_];
#pragma unroll
    for (int k = 0; k < EPT_; ++k) {
        ev[k] = ep[k * 256 + threadIdx.x];
        atomicAdd(&hist[ev[k].x >> SH2_], 1);
    }
    __syncthreads();
    if (threadIdx.x < G2_)
        cur[threadIdx.x] = atomicAdd(&gcount[bc * G2_ + threadIdx.x], hist[threadIdx.x]);
    __syncthreads();
#pragma unroll
    for (int k = 0; k < EPT_; ++k) {
        int g   = ev[k].x >> SH2_;
        int off = atomicAdd(&cur[g], 1);
        bpack[((size_t)bc * G2_ + g) * CAPF_ + off] =
            ((unsigned int)(ev[k].x & (NB2_ - 1)) << 16) | (unsigned int)ev[k].y;
    }
}

// fine pass: one block per (bc,bucket) — counting-sort 128 nodes in LDS,
// compute ee, per-node denom, write csr/rs/rd coalesced
__global__ void gat_fine(const unsigned int* __restrict__ bpack,
                         const int* __restrict__ gcount,
                         const float* __restrict__ y1, const float* __restrict__ y0,
                         unsigned short* __restrict__ csr_i1, float* __restrict__ csr_ee,
                         int* __restrict__ rs_s, int* __restrict__ rs_e,
                         float* __restrict__ rd) {
    int bc = blockIdx.x & 7;
    int g  = blockIdx.x >> 3;               // 0..78
    int K  = gcount[bc * G2_ + g];
    int R  = (bc * G2_ + g) * CAPF_;        // absolute csr base for this bucket
    const unsigned int* bp = bpack + R;
    const float* y1p = y1 + bc * N_;
    int tid = threadIdx.x;

    __shared__ int   cnt[NB2_], excl[NB2_], cur[NB2_], sd[NB2_];
    __shared__ float y0l[NB2_];
    __shared__ unsigned short li1[CAPF_];
    __shared__ float lee[CAPF_];

    int node = g * NB2_ + tid;
    if (tid < NB2_) {
        cnt[tid] = 0;
        y0l[tid] = (node < N_) ? y0[bc * N_ + node] : 0.f;
    }
    __syncthreads();

    for (int j = tid; j < K; j += 256)
        atomicAdd(&cnt[bp[j] >> 16], 1);
    __syncthreads();

    // exclusive scan of cnt[128] (Hillis-Steele, barriers block-uniform)
    int v = 0;
    if (tid < NB2_) { v = cnt[tid]; sd[tid] = v; }
    __syncthreads();
    for (int off = 1; off < NB2_; off <<= 1) {
        int t = (tid < NB2_ && tid >= off) ? sd[tid - off] : 0;
        __syncthreads();
        if (tid < NB2_) sd[tid] += t;
        __syncthreads();
    }
    if (tid < NB2_) {
        int ex = sd[tid] - v;
        excl[tid] = ex;
        cur[tid]  = ex;
        if (node < N_) {
            rs_s[bc * N_ + node] = R + ex;
            rs_e[bc * N_ + node] = R + ex + v;
        }
    }
    __syncthreads();

    for (int j = tid; j < K; j += 256) {
        unsigned int p = bp[j];
        int ln = p >> 16;
        int i1 = p & 0xffff;
        int slot = atomicAdd(&cur[ln], 1);
        li1[slot] = (unsigned short)i1;
        float sc = y1p[i1] + y0l[ln];
        lee[slot] = __expf(sc > 0.f ? sc : 0.2f * sc);
    }
    __syncthreads();

    if (tid < NB2_ && node < N_) {
        int s = excl[tid], t = s + v;
        float sum = 0.f;
        for (int j = s; j < t; ++j) sum += lee[j];
        rd[bc * N_ + node] = 1.f / (sum + EPS_);
    }
    for (int j = tid; j < K; j += 256) {
        csr_i1[R + j] = li1[j];
        csr_ee[R + j] = lee[j];
    }
}

// wave per (b,n,c): lane-parallel metadata (w_j = ev_j * rd[a_j]), then per-edge
// shfl-broadcast + x-row load + fma, unrolled x8 with zero padding
__global__ void gat_acc(const float* __restrict__ x, const int* __restrict__ rs_s,
                        const int* __restrict__ rs_e,
                        const unsigned short* __restrict__ csr_i1,
                        const float* __restrict__ csr_ee, const float* __restrict__ rd,
                        float* __restrict__ out) {
    int lane = threadIdx.x & 63;
    int w    = threadIdx.x >> 6;               // 0..3
    int b    = blockIdx.x & 3;                 // batch XCD-affine
    int nn   = blockIdx.x >> 2;                // 0..4999
    int n    = nn * 2 + (w >> 1);
    int c    = w & 1;
    int bc = b * C_ + c;
    const float* xb  = x + (size_t)b * N_ * D_ + lane;
    const float* rdp = rd + bc * N_;
    int s = rs_s[bc * N_ + n], t = rs_e[bc * N_ + n];
    float acc = 0.f;
    for (int base = s; base < t; base += 64) {
        int m = t - base; if (m > 64) m = 64;
        int a = 0; float wgt = 0.f;
        if (lane < m) {
            a   = csr_i1[base + lane];             // coalesced u16
            wgt = csr_ee[base + lane] * rdp[a];    // coalesced + hot gather
        }
        int mp = (m + 7) & ~7;
        for (int j = 0; j < mp; j += 8) {
            int   a0 = __shfl(a, j),     a1 = __shfl(a, j + 1);
            int   a2 = __shfl(a, j + 2), a3 = __shfl(a, j + 3);
            int   a4 = __shfl(a, j + 4), a5 = __shfl(a, j + 5);
            int   a6 = __shfl(a, j + 6), a7 = __shfl(a, j + 7);
            float w0 = __shfl(wgt, j),     w1 = __shfl(wgt, j + 1);
            float w2 = __shfl(wgt, j + 2), w3 = __shfl(wgt, j + 3);
            float w4 = __shfl(wgt, j + 4), w5 = __shfl(wgt, j + 5);
            float w6 = __shfl(wgt, j + 6), w7 = __shfl(wgt, j + 7);
            float x0 = xb[a0 * D_], x1 = xb[a1 * D_];
            float x2 = xb[a2 * D_], x3 = xb[a3 * D_];
            float x4 = xb[a4 * D_], x5 = xb[a5 * D_];
            float x6 = xb[a6 * D_], x7 = xb[a7 * D_];
            acc += w0 * x0;
            acc += w1 * x1;
            acc += w2 * x2;
            acc += w3 * x3;
            acc += w4 * x4;
            acc += w5 * x5;
            acc += w6 * x6;
            acc += w7 * x7;
        }
    }
    float sg = 1.f / (1.f + __expf(-acc));
    __shared__ float sh[2][64];
    if (c == 1) sh[w >> 1][lane] = sg;
    __syncthreads();
    if (c == 0) out[((size_t)b * N_ + n) * D_ + lane] = sg + sh[w >> 1][lane];
}

extern "C" void kernel_launch(void* const* d_in, const int* in_sizes, int n_in,
                              void* d_out, int out_size, void* d_ws, size_t ws_size,
                              hipStream_t stream) {
    const float* x    = (const float*)d_in[0];
    const int*   eidx = (const int*)d_in[1];
    const float* wa   = (const float*)d_in[2];
    float* out = (float*)d_out;

    int*   gcount = (int*)d_ws;                                  // BC*G2 (pad 1024)
    float* y1     = (float*)d_ws + 1024;                         // BC*N
    float* y0     = y1 + BC_ * N_;                               // BC*N
    float* rd     = y0 + BC_ * N_;                               // BC*N
    int*   rs_s   = (int*)(rd + BC_ * N_);                       // BC*N
    int*   rs_e   = rs_s + BC_ * N_;                             // BC*N
    unsigned int* bpack  = (unsigned int*)(rs_e + BC_ * N_);     // BC*G2*CAPF
    float*        csr_ee = (float*)(bpack + (size_t)BC_ * G2_ * CAPF_); // BC*G2*CAPF
    unsigned short* csr_i1 = (unsigned short*)(csr_ee + (size_t)BC_ * G2_ * CAPF_);

    hipMemsetAsync(gcount, 0, BC_ * G2_ * sizeof(int), stream);

    gat_y     <<<BC_ * 40,    256, 0, stream>>>(x, wa, y1, y0);
    gat_bucket<<<BC_ * NBLK_, 256, 0, stream>>>(eidx, gcount, bpack);
    gat_fine  <<<BC_ * G2_,   256, 0, stream>>>(bpack, gcount, y1, y0,
                                                csr_i1, csr_ee, rs_s, rs_e, rd);
    gat_acc   <<<B_ * N_ / 2, 256, 0, stream>>>(x, rs_s, rs_e, csr_i1, csr_ee, rd, out);
}

// Round 8
// 133.127 us; speedup vs baseline: 3.3077x; 1.0352x over previous
//
#include <hip/hip_runtime.h>

#define B_ 4
#define N_ 10000
#define D_ 64
#define C_ 2
#define E_ 160000
#define BC_ (B_ * C_)
#define SH2_ 7                  // 128 nodes per fine bucket
#define NB2_ 128
#define G2_ 79                  // ceil(10000/128)
#define CAPF_ 2560              // slots per (bc,bucket); mean 2048, +11 sigma
#define NBLK_ 125               // bucket-pass blocks per bc
#define EPT_ 5                  // edges per thread in bucket pass
#define EPB_ (256 * EPT_)       // 1280 edges per block
#define YBLK_ (BC_ * 40)        // y-phase blocks fused into gat_yb
#define EPS_ 1e-10f

// Fused kernel: blocks [0,YBLK_) compute per-node dots y1/y0; the remaining
// 1000 blocks run the coarse bucket pass with an in-LDS counting sort by
// bucket so global bpack writes are dense runs (kills line amplification).
__global__ void gat_yb(const float* __restrict__ x, const float* __restrict__ wa,
                       float* __restrict__ y1, float* __restrict__ y0,
                       const int* __restrict__ eidx, int* __restrict__ gcount,
                       unsigned int* __restrict__ bpack) {
    int tid = threadIdx.x;
    if (blockIdx.x < YBLK_) {
        int bc = blockIdx.x & 7;
        int n  = (blockIdx.x >> 3) * 256 + tid;
        if (n >= N_) return;
        int b = bc / C_, c = bc % C_;
        const float4* xr = (const float4*)(x + ((size_t)b * N_ + n) * D_);
        const float4* w1 = (const float4*)(wa + (size_t)c * 2 * D_);
        const float4* w0 = w1 + D_ / 4;
        float a = 0.f, bb = 0.f;
#pragma unroll
        for (int i = 0; i < D_ / 4; ++i) {
            float4 xv = xr[i];
            float4 u = w1[i], v = w0[i];
            a  += xv.x * u.x + xv.y * u.y + xv.z * u.z + xv.w * u.w;
            bb += xv.x * v.x + xv.y * v.y + xv.z * v.z + xv.w * v.w;
        }
        y1[bc * N_ + n] = a;
        y0[bc * N_ + n] = bb;
        return;
    }
    // ---- bucket phase ----
    int bid = blockIdx.x - YBLK_;
    int bc  = bid & 7;
    int blk = bid >> 3;                     // 0..124
    const int2* ep = (const int2*)eidx + (size_t)bc * E_ + (size_t)blk * EPB_;
    __shared__ int sd[128];                 // hist then inclusive scan
    __shared__ int excl[G2_], cur[G2_], gbase[G2_];
    __shared__ unsigned int stage[EPB_];
    if (tid < 128) sd[tid] = 0;
    __syncthreads();
    unsigned int pk[EPT_];
    int gg[EPT_];
#pragma unroll
    for (int k = 0; k < EPT_; ++k) {
        int2 v = ep[k * 256 + tid];
        int g  = v.x >> SH2_;               // 0..78
        gg[k]  = g;
        pk[k]  = ((unsigned int)g << 21) |
                 ((unsigned int)(v.x & (NB2_ - 1)) << 14) |
                 (unsigned int)v.y;         // g:7 | ln:7 | i1:14
        atomicAdd(&sd[g], 1);
    }
    __syncthreads();
    int cnt = (tid < 128) ? sd[tid] : 0;
    for (int off = 1; off < 128; off <<= 1) {
        int t = (tid < 128 && tid >= off) ? sd[tid - off] : 0;
        __syncthreads();
        if (tid < 128) sd[tid] += t;
        __syncthreads();
    }
    if (tid < G2_) {
        int ex = sd[tid] - cnt;
        excl[tid]  = ex;
        cur[tid]   = ex;
        gbase[tid] = atomicAdd(&gcount[bc * G2_ + tid], cnt);  // one atomic per (block,g)
    }
    __syncthreads();
#pragma unroll
    for (int k = 0; k < EPT_; ++k) {
        int slot = atomicAdd(&cur[gg[k]], 1);
        stage[slot] = pk[k];
    }
    __syncthreads();
    // sorted writeout: consecutive threads hit consecutive addresses per run
#pragma unroll
    for (int k = 0; k < EPT_; ++k) {
        int idx = k * 256 + tid;
        unsigned int p = stage[idx];
        int g     = p >> 21;
        int local = idx - excl[g];
        bpack[((size_t)bc * G2_ + g) * CAPF_ + gbase[g] + local] =
            (((p >> 14) & 127u) << 16) | (p & 16383u);
    }
}

// fine pass: one block per (bc,bucket) — counting-sort 128 nodes in LDS,
// compute ee, per-node denom, write csr/rs/rd coalesced
__global__ void gat_fine(const unsigned int* __restrict__ bpack,
                         const int* __restrict__ gcount,
                         const float* __restrict__ y1, const float* __restrict__ y0,
                         unsigned short* __restrict__ csr_i1, float* __restrict__ csr_ee,
                         int* __restrict__ rs_s, int* __restrict__ rs_e,
                         float* __restrict__ rd) {
    int bc = blockIdx.x & 7;
    int g  = blockIdx.x >> 3;               // 0..78
    int K  = gcount[bc * G2_ + g];
    int R  = (bc * G2_ + g) * CAPF_;        // absolute csr base for this bucket
    const unsigned int* bp = bpack + R;
    const float* y1p = y1 + bc * N_;
    int tid = threadIdx.x;

    __shared__ int   cnt[NB2_], excl[NB2_], cur[NB2_], sd[NB2_];
    __shared__ float y0l[NB2_];
    __shared__ unsigned short li1[CAPF_];
    __shared__ float lee[CAPF_];

    int node = g * NB2_ + tid;
    if (tid < NB2_) {
        cnt[tid] = 0;
        y0l[tid] = (node < N_) ? y0[bc * N_ + node] : 0.f;
    }
    __syncthreads();

    for (int j = tid; j < K; j += 256)
        atomicAdd(&cnt[bp[j] >> 16], 1);
    __syncthreads();

    int v = 0;
    if (tid < NB2_) { v = cnt[tid]; sd[tid] = v; }
    __syncthreads();
    for (int off = 1; off < NB2_; off <<= 1) {
        int t = (tid < NB2_ && tid >= off) ? sd[tid - off] : 0;
        __syncthreads();
        if (tid < NB2_) sd[tid] += t;
        __syncthreads();
    }
    if (tid < NB2_) {
        int ex = sd[tid] - v;
        excl[tid] = ex;
        cur[tid]  = ex;
        if (node < N_) {
            rs_s[bc * N_ + node] = R + ex;
            rs_e[bc * N_ + node] = R + ex + v;
        }
    }
    __syncthreads();

    for (int j = tid; j < K; j += 256) {
        unsigned int p = bp[j];
        int ln = p >> 16;
        int i1 = p & 0xffff;
        int slot = atomicAdd(&cur[ln], 1);
        li1[slot] = (unsigned short)i1;
        float sc = y1p[i1] + y0l[ln];
        lee[slot] = __expf(sc > 0.f ? sc : 0.2f * sc);
    }
    __syncthreads();

    if (tid < NB2_ && node < N_) {
        int s = excl[tid], t = s + v;
        float sum = 0.f;
        for (int j = s; j < t; ++j) sum += lee[j];
        rd[bc * N_ + node] = 1.f / (sum + EPS_);
    }
    for (int j = tid; j < K; j += 256) {
        csr_i1[R + j] = li1[j];
        csr_ee[R + j] = lee[j];
    }
}

// wave per (b,n,c): lane-parallel metadata (w_j = ev_j * rd[a_j]), then per-edge
// shfl-broadcast + x-row load + fma, unrolled x8 with zero padding
__global__ void gat_acc(const float* __restrict__ x, const int* __restrict__ rs_s,
                        const int* __restrict__ rs_e,
                        const unsigned short* __restrict__ csr_i1,
                        const float* __restrict__ csr_ee, const float* __restrict__ rd,
                        float* __restrict__ out) {
    int lane = threadIdx.x & 63;
    int w    = threadIdx.x >> 6;               // 0..3
    int b    = blockIdx.x & 3;                 // batch XCD-affine
    int nn   = blockIdx.x >> 2;                // 0..4999
    int n    = nn * 2 + (w >> 1);
    int c    = w & 1;
    int bc = b * C_ + c;
    const float* xb  = x + (size_t)b * N_ * D_ + lane;
    const float* rdp = rd + bc * N_;
    int s = rs_s[bc * N_ + n], t = rs_e[bc * N_ + n];
    float acc = 0.f;
    for (int base = s; base < t; base += 64) {
        int m = t - base; if (m > 64) m = 64;
        int a = 0; float wgt = 0.f;
        if (lane < m) {
            a   = csr_i1[base + lane];             // coalesced u16
            wgt = csr_ee[base + lane] * rdp[a];    // coalesced + hot gather
        }
        int mp = (m + 7) & ~7;
        for (int j = 0; j < mp; j += 8) {
            int   a0 = __shfl(a, j),     a1 = __shfl(a, j + 1);
            int   a2 = __shfl(a, j + 2), a3 = __shfl(a, j + 3);
            int   a4 = __shfl(a, j + 4), a5 = __shfl(a, j + 5);
            int   a6 = __shfl(a, j + 6), a7 = __shfl(a, j + 7);
            float w0 = __shfl(wgt, j),     w1 = __shfl(wgt, j + 1);
            float w2 = __shfl(wgt, j + 2), w3 = __shfl(wgt, j + 3);
            float w4 = __shfl(wgt, j + 4), w5 = __shfl(wgt, j + 5);
            float w6 = __shfl(wgt, j + 6), w7 = __shfl(wgt, j + 7);
            float x0 = xb[a0 * D_], x1 = xb[a1 * D_];
            float x2 = xb[a2 * D_], x3 = xb[a3 * D_];
            float x4 = xb[a4 * D_], x5 = xb[a5 * D_];
            float x6 = xb[a6 * D_], x7 = xb[a7 * D_];
            acc += w0 * x0;
            acc += w1 * x1;
            acc += w2 * x2;
            acc += w3 * x3;
            acc += w4 * x4;
            acc += w5 * x5;
            acc += w6 * x6;
            acc += w7 * x7;
        }
    }
    float sg = 1.f / (1.f + __expf(-acc));
    __shared__ float sh[2][64];
    if (c == 1) sh[w >> 1][lane] = sg;
    __syncthreads();
    if (c == 0) out[((size_t)b * N_ + n) * D_ + lane] = sg + sh[w >> 1][lane];
}

extern "C" void kernel_launch(void* const* d_in, const int* in_sizes, int n_in,
                              void* d_out, int out_size, void* d_ws, size_t ws_size,
                              hipStream_t stream) {
    const float* x    = (const float*)d_in[0];
    const int*   eidx = (const int*)d_in[1];
    const float* wa   = (const float*)d_in[2];
    float* out = (float*)d_out;

    int*   gcount = (int*)d_ws;                                  // BC*G2 (pad 1024)
    float* y1     = (float*)d_ws + 1024;                         // BC*N
    float* y0     = y1 + BC_ * N_;                               // BC*N
    float* rd     = y0 + BC_ * N_;                               // BC*N
    int*   rs_s   = (int*)(rd + BC_ * N_);                       // BC*N
    int*   rs_e   = rs_s + BC_ * N_;                             // BC*N
    unsigned int* bpack  = (unsigned int*)(rs_e + BC_ * N_);     // BC*G2*CAPF
    float*        csr_ee = (float*)(bpack + (size_t)BC_ * G2_ * CAPF_); // BC*G2*CAPF
    unsigned short* csr_i1 = (unsigned short*)(csr_ee + (size_t)BC_ * G2_ * CAPF_);

    hipMemsetAsync(gcount, 0, BC_ * G2_ * sizeof(int), stream);

    gat_yb  <<<YBLK_ + BC_ * NBLK_, 256, 0, stream>>>(x, wa, y1, y0, eidx, gcount, bpack);
    gat_fine<<<BC_ * G2_,           256, 0, stream>>>(bpack, gcount, y1, y0,
                                                      csr_i1, csr_ee, rs_s, rs_e, rd);
    gat_acc <<<B_ * N_ / 2,         256, 0, stream>>>(x, rs_s, rs_e, csr_i1, csr_ee, rd, out);
}

// Round 9
// 129.288 us; speedup vs baseline: 3.4059x; 1.0297x over previous
//
#include <hip/hip_runtime.h>

#define B_ 4
#define N_ 10000
#define D_ 64
#define C_ 2
#define E_ 160000
#define BC_ (B_ * C_)
#define SH2_ 7                  // 128 nodes per fine bucket
#define NB2_ 128
#define G2_ 79                  // ceil(10000/128)
#define CAPF_ 2560              // slots per (bc,bucket); mean 2048, +11 sigma
#define NBLK_ 125               // bucket-pass blocks per bc
#define EPT_ 5                  // edges per thread in bucket pass
#define EPB_ (256 * EPT_)       // 1280 edges per block
#define YBLK_ (BC_ * 40)        // y-phase blocks fused into gat_yb
#define EPS_ 1e-10f

// Fused kernel: blocks [0,YBLK_) compute per-node dots y1/y0; the remaining
// 1000 blocks run the coarse bucket pass with an in-LDS counting sort by
// bucket so global bpack writes are dense runs.
__global__ void gat_yb(const float* __restrict__ x, const float* __restrict__ wa,
                       float* __restrict__ y1, float* __restrict__ y0,
                       const int* __restrict__ eidx, int* __restrict__ gcount,
                       unsigned int* __restrict__ bpack) {
    int tid = threadIdx.x;
    if (blockIdx.x < YBLK_) {
        int bc = blockIdx.x & 7;
        int n  = (blockIdx.x >> 3) * 256 + tid;
        if (n >= N_) return;
        int b = bc / C_, c = bc % C_;
        const float4* xr = (const float4*)(x + ((size_t)b * N_ + n) * D_);
        const float4* w1 = (const float4*)(wa + (size_t)c * 2 * D_);
        const float4* w0 = w1 + D_ / 4;
        float a = 0.f, bb = 0.f;
#pragma unroll
        for (int i = 0; i < D_ / 4; ++i) {
            float4 xv = xr[i];
            float4 u = w1[i], v = w0[i];
            a  += xv.x * u.x + xv.y * u.y + xv.z * u.z + xv.w * u.w;
            bb += xv.x * v.x + xv.y * v.y + xv.z * v.z + xv.w * v.w;
        }
        y1[bc * N_ + n] = a;
        y0[bc * N_ + n] = bb;
        return;
    }
    // ---- bucket phase ----
    int bid = blockIdx.x - YBLK_;
    int bc  = bid & 7;
    int blk = bid >> 3;                     // 0..124
    const int2* ep = (const int2*)eidx + (size_t)bc * E_ + (size_t)blk * EPB_;
    __shared__ int sd[128];                 // hist then inclusive scan
    __shared__ int excl[G2_], cur[G2_], gbase[G2_];
    __shared__ unsigned int stage[EPB_];
    if (tid < 128) sd[tid] = 0;
    __syncthreads();
    unsigned int pk[EPT_];
    int gg[EPT_];
#pragma unroll
    for (int k = 0; k < EPT_; ++k) {
        int2 v = ep[k * 256 + tid];
        int g  = v.x >> SH2_;               // 0..78
        gg[k]  = g;
        pk[k]  = ((unsigned int)g << 21) |
                 ((unsigned int)(v.x & (NB2_ - 1)) << 14) |
                 (unsigned int)v.y;         // g:7 | ln:7 | i1:14
        atomicAdd(&sd[g], 1);
    }
    __syncthreads();
    int cnt = (tid < 128) ? sd[tid] : 0;
    for (int off = 1; off < 128; off <<= 1) {
        int t = (tid < 128 && tid >= off) ? sd[tid - off] : 0;
        __syncthreads();
        if (tid < 128) sd[tid] += t;
        __syncthreads();
    }
    if (tid < G2_) {
        int ex = sd[tid] - cnt;
        excl[tid]  = ex;
        cur[tid]   = ex;
        gbase[tid] = atomicAdd(&gcount[bc * G2_ + tid], cnt);
    }
    __syncthreads();
#pragma unroll
    for (int k = 0; k < EPT_; ++k) {
        int slot = atomicAdd(&cur[gg[k]], 1);
        stage[slot] = pk[k];
    }
    __syncthreads();
#pragma unroll
    for (int k = 0; k < EPT_; ++k) {
        int idx = k * 256 + tid;
        unsigned int p = stage[idx];
        int g     = p >> 21;
        int local = idx - excl[g];
        bpack[((size_t)bc * G2_ + g) * CAPF_ + gbase[g] + local] =
            (((p >> 14) & 127u) << 16) | (p & 16383u);
    }
}

// fine pass: one block per (bc,bucket) — denom via LDS float atomics on the
// coalesced ev pass (no sort needed for denom), then counting-sort i1 only;
// writes sorted csr_i1 (u16), rs_s/rs_e, and yrd = {y1, 1/(den+eps)}
__global__ void gat_fine(const unsigned int* __restrict__ bpack,
                         const int* __restrict__ gcount,
                         const float* __restrict__ y1, const float* __restrict__ y0,
                         unsigned short* __restrict__ csr_i1,
                         int* __restrict__ rs_s, int* __restrict__ rs_e,
                         float2* __restrict__ yrd) {
    int bc = blockIdx.x & 7;
    int g  = blockIdx.x >> 3;               // 0..78
    int K  = gcount[bc * G2_ + g];
    int R  = (bc * G2_ + g) * CAPF_;        // absolute csr base for this bucket
    const unsigned int* bp = bpack + R;
    const float* y1p = y1 + bc * N_;
    int tid = threadIdx.x;

    __shared__ int   cnt[NB2_], excl[NB2_], cur[NB2_], sd[NB2_];
    __shared__ float y0l[NB2_], den[NB2_];
    __shared__ unsigned short li1[CAPF_];

    int node = g * NB2_ + tid;
    if (tid < NB2_) {
        cnt[tid] = 0;
        den[tid] = 0.f;
        y0l[tid] = (node < N_) ? y0[bc * N_ + node] : 0.f;
    }
    __syncthreads();

    // coalesced pass: histogram + denom accumulation (order-free)
    for (int j = tid; j < K; j += 256) {
        unsigned int p = bp[j];
        int ln = p >> 16;
        int i1 = p & 0xffff;
        float sc = y1p[i1] + y0l[ln];
        float ev = __expf(sc > 0.f ? sc : 0.2f * sc);
        atomicAdd(&cnt[ln], 1);
        atomicAdd(&den[ln], ev);
    }
    __syncthreads();

    int v = 0;
    if (tid < NB2_) { v = cnt[tid]; sd[tid] = v; }
    __syncthreads();
    for (int off = 1; off < NB2_; off <<= 1) {
        int t = (tid < NB2_ && tid >= off) ? sd[tid - off] : 0;
        __syncthreads();
        if (tid < NB2_) sd[tid] += t;
        __syncthreads();
    }
    if (tid < NB2_) {
        int ex = sd[tid] - v;
        excl[tid] = ex;
        cur[tid]  = ex;
        if (node < N_) {
            rs_s[bc * N_ + node] = R + ex;
            rs_e[bc * N_ + node] = R + ex + v;
            yrd[bc * N_ + node]  = make_float2(y1p[node], 1.f / (den[tid] + EPS_));
        }
    }
    __syncthreads();

    for (int j = tid; j < K; j += 256) {
        unsigned int p = bp[j];
        int slot = atomicAdd(&cur[p >> 16], 1);
        li1[slot] = (unsigned short)(p & 0xffff);
    }
    __syncthreads();

    for (int j = tid; j < K; j += 256)
        csr_i1[R + j] = li1[j];
}

// wave per (b,n,c): lane-parallel metadata — a = i1, wgt = exp(lrelu(y1[a]+y0[n]))
// * rd[a] from one packed float2 gather — staged in per-wave LDS; fma loop does
// one uniform ds_read_b64 broadcast per edge, unrolled x8
__global__ void gat_acc(const float* __restrict__ x, const int* __restrict__ rs_s,
                        const int* __restrict__ rs_e,
                        const unsigned short* __restrict__ csr_i1,
                        const float2* __restrict__ yrd, const float* __restrict__ y0,
                        float* __restrict__ out) {
    int lane = threadIdx.x & 63;
    int w    = threadIdx.x >> 6;               // 0..3
    int b    = blockIdx.x & 3;                 // batch XCD-affine
    int nn   = blockIdx.x >> 2;                // 0..4999
    int n    = nn * 2 + (w >> 1);
    int c    = w & 1;
    int bc = b * C_ + c;
    const float* xb = x + (size_t)b * N_ * D_ + lane;
    const float2* yrdp = yrd + bc * N_;
    int s = rs_s[bc * N_ + n], t = rs_e[bc * N_ + n];
    float y0n = y0[bc * N_ + n];
    __shared__ float2 meta[4][64];
    float acc = 0.f;
    for (int base = s; base < t; base += 64) {
        int m = t - base; if (m > 64) m = 64;
        int a = 0; float wgt = 0.f;
        if (lane < m) {
            a = csr_i1[base + lane];               // coalesced u16
            float2 yr = yrdp[a];                   // packed {y1, rd} gather
            float sc = yr.x + y0n;
            wgt = __expf(sc > 0.f ? sc : 0.2f * sc) * yr.y;
        }
        meta[w][lane] = make_float2(__int_as_float(a), wgt);
        int mp = (m + 7) & ~7;
        for (int j = 0; j < mp; j += 8) {
            float2 m0 = meta[w][j],     m1 = meta[w][j + 1];
            float2 m2 = meta[w][j + 2], m3 = meta[w][j + 3];
            float2 m4 = meta[w][j + 4], m5 = meta[w][j + 5];
            float2 m6 = meta[w][j + 6], m7 = meta[w][j + 7];
            float x0 = xb[__float_as_int(m0.x) * D_], x1 = xb[__float_as_int(m1.x) * D_];
            float x2 = xb[__float_as_int(m2.x) * D_], x3 = xb[__float_as_int(m3.x) * D_];
            float x4 = xb[__float_as_int(m4.x) * D_], x5 = xb[__float_as_int(m5.x) * D_];
            float x6 = xb[__float_as_int(m6.x) * D_], x7 = xb[__float_as_int(m7.x) * D_];
            acc += m0.y * x0;
            acc += m1.y * x1;
            acc += m2.y * x2;
            acc += m3.y * x3;
            acc += m4.y * x4;
            acc += m5.y * x5;
            acc += m6.y * x6;
            acc += m7.y * x7;
        }
    }
    float sg = 1.f / (1.f + __expf(-acc));
    __shared__ float sh[2][64];
    if (c == 1) sh[w >> 1][lane] = sg;
    __syncthreads();
    if (c == 0) out[((size_t)b * N_ + n) * D_ + lane] = sg + sh[w >> 1][lane];
}

extern "C" void kernel_launch(void* const* d_in, const int* in_sizes, int n_in,
                              void* d_out, int out_size, void* d_ws, size_t ws_size,
                              hipStream_t stream) {
    const float* x    = (const float*)d_in[0];
    const int*   eidx = (const int*)d_in[1];
    const float* wa   = (const float*)d_in[2];
    float* out = (float*)d_out;

    int*    gcount = (int*)d_ws;                              // BC*G2 (pad 1024)
    float*  y1     = (float*)d_ws + 1024;                     // BC*N
    float*  y0     = y1 + BC_ * N_;                           // BC*N
    float2* yrd    = (float2*)(y0 + BC_ * N_);                // BC*N float2
    int*    rs_s   = (int*)(yrd + BC_ * N_);                  // BC*N
    int*    rs_e   = rs_s + BC_ * N_;                         // BC*N
    unsigned int* bpack = (unsigned int*)(rs_e + BC_ * N_);   // BC*G2*CAPF
    unsigned short* csr_i1 = (unsigned short*)(bpack + (size_t)BC_ * G2_ * CAPF_);

    hipMemsetAsync(gcount, 0, BC_ * G2_ * sizeof(int), stream);

    gat_yb  <<<YBLK_ + BC_ * NBLK_, 256, 0, stream>>>(x, wa, y1, y0, eidx, gcount, bpack);
    gat_fine<<<BC_ * G2_,           256, 0, stream>>>(bpack, gcount, y1, y0,
                                                      csr_i1, rs_s, rs_e, yrd);
    gat_acc <<<B_ * N_ / 2,         256, 0, stream>>>(x, rs_s, rs_e, csr_i1, yrd, y0, out);
}